// Round 1
// 4448.640 us; speedup vs baseline: 1.3245x; 1.3245x over previous
//
#include <hip/hip_runtime.h>
#include <math.h>

#define B_  64
#define T_  2048
#define V_  512
#define H_  256
#define D_  128
#define VD_ 8

// Barrier WITHOUT vmcnt drain: only LDS (lgkmcnt) ordering is required across
// the intra-step barriers. __syncthreads() would drain the in-flight z
// prefetch (HBM, ~500cy) and H_all store every phase — pure stall.
// No cross-thread dependency flows through global memory inside the loop.
#define BAR() asm volatile("s_waitcnt lgkmcnt(0)\n\ts_barrier" ::: "memory")

// ---------------------------------------------------------------------------
// Generic NT GEMM: C[m,n] = bias[n] + sum_k A[m,k] * B[n,k]   (unchanged)
// ---------------------------------------------------------------------------
__global__ __launch_bounds__(256) void gemm_nt_kernel(
    const float* __restrict__ A, const float* __restrict__ Bm,
    const float* __restrict__ bias, float* __restrict__ C,
    int M, int N, int K)
{
    __shared__ float As[32][68];
    __shared__ float Bs[32][260];

    const int m0  = blockIdx.x * 64;
    const int n0  = blockIdx.y * 256;
    const int tid = threadIdx.x;
    const int tm  = tid >> 4;
    const int tn  = tid & 15;

    float acc[4][4][4];
    #pragma unroll
    for (int i = 0; i < 4; i++)
      #pragma unroll
      for (int cb = 0; cb < 4; cb++)
        #pragma unroll
        for (int jj = 0; jj < 4; jj++) acc[i][cb][jj] = 0.f;

    for (int kc = 0; kc < K; kc += 32) {
        #pragma unroll
        for (int rep = 0; rep < 2; rep++) {
            int f  = tid + rep * 256;
            int mm = f >> 3;
            int k4 = (f & 7) << 2;
            float4 v = *(const float4*)(A + (size_t)(m0 + mm) * K + kc + k4);
            As[k4 + 0][mm] = v.x;
            As[k4 + 1][mm] = v.y;
            As[k4 + 2][mm] = v.z;
            As[k4 + 3][mm] = v.w;
        }
        #pragma unroll
        for (int rep = 0; rep < 8; rep++) {
            int f  = tid + rep * 256;
            int nn = f >> 3;
            int k4 = (f & 7) << 2;
            float4 v = *(const float4*)(Bm + (size_t)(n0 + nn) * K + kc + k4);
            Bs[k4 + 0][nn] = v.x;
            Bs[k4 + 1][nn] = v.y;
            Bs[k4 + 2][nn] = v.z;
            Bs[k4 + 3][nn] = v.w;
        }
        __syncthreads();

        #pragma unroll
        for (int kk = 0; kk < 32; kk++) {
            float4 a = *(const float4*)&As[kk][4 * tm];
            #pragma unroll
            for (int cb = 0; cb < 4; cb++) {
                float4 b = *(const float4*)&Bs[kk][64 * cb + 4 * tn];
                acc[0][cb][0] += a.x * b.x; acc[0][cb][1] += a.x * b.y;
                acc[0][cb][2] += a.x * b.z; acc[0][cb][3] += a.x * b.w;
                acc[1][cb][0] += a.y * b.x; acc[1][cb][1] += a.y * b.y;
                acc[1][cb][2] += a.y * b.z; acc[1][cb][3] += a.y * b.w;
                acc[2][cb][0] += a.z * b.x; acc[2][cb][1] += a.z * b.y;
                acc[2][cb][2] += a.z * b.z; acc[2][cb][3] += a.z * b.w;
                acc[3][cb][0] += a.w * b.x; acc[3][cb][1] += a.w * b.y;
                acc[3][cb][2] += a.w * b.z; acc[3][cb][3] += a.w * b.w;
            }
        }
        __syncthreads();
    }

    #pragma unroll
    for (int cb = 0; cb < 4; cb++) {
        int c = n0 + 64 * cb + 4 * tn;
        float4 bv;
        if (bias) bv = *(const float4*)(bias + c);
        else      bv = make_float4(0.f, 0.f, 0.f, 0.f);
        #pragma unroll
        for (int i = 0; i < 4; i++) {
            int r = m0 + 4 * tm + i;
            float4 v = make_float4(acc[i][cb][0] + bv.x, acc[i][cb][1] + bv.y,
                                   acc[i][cb][2] + bv.z, acc[i][cb][3] + bv.w);
            *(float4*)(C + (size_t)r * N + c) = v;
        }
    }
}

// ---------------------------------------------------------------------------
// Recurrence v2: one block per batch element, 512 threads (8 waves).
//
// Matvec is k-split across waves: wave w owns k-slice [32w,32w+32). Lane l
// accumulates FOUR outputs {l, l+64, l+128, l+192} from the SAME 32 h-values
// (8 broadcast ds_read_b128 per thread instead of 32) -> LDS return traffic
// for the h broadcast drops 4x (256KB -> 64KB per step). Cross-wave reduce
// goes through sh_part (8KB write + 8KB read, conflict-free).
//
// 4 phases / 4 light barriers per step:
//   P1 all waves : partial dots -> sh_part                      BAR
//   P2 waves 0-3 : reduce 8 partials + z + bhh, tanh, store     BAR
//   P3 waves 0-2 : gate dots (W_a/W_n rows in VGPRs), softmax/
//                  sigmoid by lane 0 of each wave               BAR
//   P4 waves 4-7 : stack blend (float4)      (runs concurrently)
//      waves 0-3 : recompute new stack top in regs + h_tilde    BAR
// ---------------------------------------------------------------------------
__global__ __launch_bounds__(512, 2) void recurrence_kernel(
    const float* __restrict__ Z,        // (B,T,H)
    const float* __restrict__ stack0,   // (B,D,VD)
    const float* __restrict__ hidden0,  // (B,H)
    const float* __restrict__ W_hh,     // (H,H)
    const float* __restrict__ b_hh,     // (H)
    const float* __restrict__ W_sh,     // (H,VD)
    const float* __restrict__ W_a,      // (3,H)
    const float* __restrict__ W_n,      // (VD,H)
    float* __restrict__ H_all,          // (B,T,H)
    float* __restrict__ out_stack,      // (B,D,VD)
    float* __restrict__ out_hidden)     // (B,H)
{
    const int b   = blockIdx.x;
    const int tid = threadIdx.x;
    const int w   = tid >> 6;   // wave 0..7
    const int l   = tid & 63;   // lane

    __shared__ __align__(16) float sh_h[H_];           // h_tilde (matvec input)
    __shared__ __align__(16) float sh_hnew[H_];        // tanh output (gate input)
    __shared__ __align__(16) float sh_part[8][H_ + 4]; // per-wave k-slice partials
    __shared__ __align__(16) float sh_st[2][D_][VD_];  // double-buffered stack
    __shared__ __align__(16) float sh_n[VD_];
    __shared__ float sh_a[3];

    // W_hh fragments: outputs {l,l+64,l+128,l+192} x k-slice [32w,32w+32)
    // = 128 VGPRs. Each element of W_hh loaded exactly once per block (L2).
    float4 wreg[4][8];
    #pragma unroll
    for (int i = 0; i < 4; i++) {
        const float4* row = (const float4*)(W_hh + (size_t)(l + 64 * i) * H_ + 32 * w);
        #pragma unroll
        for (int q = 0; q < 8; q++) wreg[i][q] = row[q];
    }

    // Gate weight rows in registers (wave0: W_a rows 0-2; wave1: W_n 0-3;
    // wave2: W_n 4-7). Each lane holds elements [4l,4l+4).
    float4 wan[4];
    #pragma unroll
    for (int r = 0; r < 4; r++) wan[r] = make_float4(0.f, 0.f, 0.f, 0.f);
    if (w == 0) {
        #pragma unroll
        for (int r = 0; r < 3; r++) wan[r] = ((const float4*)(W_a + (size_t)r * H_))[l];
    } else if (w == 1) {
        #pragma unroll
        for (int r = 0; r < 4; r++) wan[r] = ((const float4*)(W_n + (size_t)r * H_))[l];
    } else if (w == 2) {
        #pragma unroll
        for (int r = 0; r < 4; r++) wan[r] = ((const float4*)(W_n + (size_t)(r + 4) * H_))[l];
    }

    // Per-output state on threads 0..255 (thread tid owns hidden index tid)
    float wsh[VD_];
    float bhh = 0.f, hidden_reg = 0.f, z_cur = 0.f;
    if (tid < H_) {
        #pragma unroll
        for (int v = 0; v < VD_; v++) wsh[v] = W_sh[tid * VD_ + v];
        bhh        = b_hh[tid];
        hidden_reg = hidden0[(size_t)b * H_ + tid];
        z_cur      = Z[(size_t)b * T_ * H_ + tid];
    }

    for (int q = tid; q < D_ * VD_; q += 512)
        (&sh_st[0][0][0])[q] = stack0[(size_t)b * D_ * VD_ + q];
    __syncthreads();

    // initial h_tilde
    if (tid < H_) {
        float ht = hidden_reg;
        #pragma unroll
        for (int v = 0; v < VD_; v++) ht += sh_st[0][0][v] * wsh[v];
        sh_h[tid] = ht;
    }
    __syncthreads();

    for (int t = 0; t < T_; t++) {
        const int p = t & 1;

        // ---- P1: partial matvec over k-slice [32w,32w+32) -----------------
        {
            const float4* hv = (const float4*)&sh_h[32 * w];  // wave-uniform
            float4 hq[8];
            #pragma unroll
            for (int q = 0; q < 8; q++) hq[q] = hv[q];
            float acc0 = 0.f, acc1 = 0.f, acc2 = 0.f, acc3 = 0.f;
            #pragma unroll
            for (int q = 0; q < 8; q++) {
                acc0 = fmaf(hq[q].x, wreg[0][q].x, acc0);
                acc0 = fmaf(hq[q].y, wreg[0][q].y, acc0);
                acc0 = fmaf(hq[q].z, wreg[0][q].z, acc0);
                acc0 = fmaf(hq[q].w, wreg[0][q].w, acc0);
                acc1 = fmaf(hq[q].x, wreg[1][q].x, acc1);
                acc1 = fmaf(hq[q].y, wreg[1][q].y, acc1);
                acc1 = fmaf(hq[q].z, wreg[1][q].z, acc1);
                acc1 = fmaf(hq[q].w, wreg[1][q].w, acc1);
                acc2 = fmaf(hq[q].x, wreg[2][q].x, acc2);
                acc2 = fmaf(hq[q].y, wreg[2][q].y, acc2);
                acc2 = fmaf(hq[q].z, wreg[2][q].z, acc2);
                acc2 = fmaf(hq[q].w, wreg[2][q].w, acc2);
                acc3 = fmaf(hq[q].x, wreg[3][q].x, acc3);
                acc3 = fmaf(hq[q].y, wreg[3][q].y, acc3);
                acc3 = fmaf(hq[q].z, wreg[3][q].z, acc3);
                acc3 = fmaf(hq[q].w, wreg[3][q].w, acc3);
            }
            sh_part[w][l]       = acc0;   // coalesced, conflict-free
            sh_part[w][l + 64]  = acc1;
            sh_part[w][l + 128] = acc2;
            sh_part[w][l + 192] = acc3;
        }
        BAR();

        // ---- P2: cross-wave reduce + tanh (waves 0-3) ---------------------
        if (tid < H_) {
            // stride 260 floats between rows -> banks 4 apart, conflict-free
            float s0 = sh_part[0][tid] + sh_part[1][tid];
            float s1 = sh_part[2][tid] + sh_part[3][tid];
            float s2 = sh_part[4][tid] + sh_part[5][tid];
            float s3 = sh_part[6][tid] + sh_part[7][tid];
            float pre = z_cur + bhh + ((s0 + s1) + (s2 + s3));
            float hn = tanhf(pre);
            hidden_reg   = hn;
            sh_hnew[tid] = hn;
            H_all[((size_t)b * T_ + t) * H_ + tid] = hn;          // fire & forget
            if (t + 1 < T_)
                z_cur = Z[((size_t)b * T_ + t + 1) * H_ + tid];   // prefetch
        }
        BAR();

        // ---- P3: gates on waves 0-2 (parallel softmax3 + sigmoid8) --------
        if (w < 3) {
            float4 hv4 = *(const float4*)&sh_hnew[4 * l];
            float g0 = hv4.x * wan[0].x + hv4.y * wan[0].y + hv4.z * wan[0].z + hv4.w * wan[0].w;
            float g1 = hv4.x * wan[1].x + hv4.y * wan[1].y + hv4.z * wan[1].z + hv4.w * wan[1].w;
            float g2 = hv4.x * wan[2].x + hv4.y * wan[2].y + hv4.z * wan[2].z + hv4.w * wan[2].w;
            float g3 = hv4.x * wan[3].x + hv4.y * wan[3].y + hv4.z * wan[3].z + hv4.w * wan[3].w;
            #pragma unroll
            for (int off = 32; off > 0; off >>= 1) {
                g0 += __shfl_xor(g0, off, 64);
                g1 += __shfl_xor(g1, off, 64);
                g2 += __shfl_xor(g2, off, 64);
                g3 += __shfl_xor(g3, off, 64);
            }
            if (l == 0) {
                if (w == 0) {
                    float m  = fmaxf(g0, fmaxf(g1, g2));
                    float e0 = expf(g0 - m), e1 = expf(g1 - m), e2 = expf(g2 - m);
                    float inv = 1.f / (e0 + e1 + e2);
                    sh_a[0] = e0 * inv; sh_a[1] = e1 * inv; sh_a[2] = e2 * inv;
                } else if (w == 1) {
                    sh_n[0] = 1.f / (1.f + expf(-g0));
                    sh_n[1] = 1.f / (1.f + expf(-g1));
                    sh_n[2] = 1.f / (1.f + expf(-g2));
                    sh_n[3] = 1.f / (1.f + expf(-g3));
                } else {
                    sh_n[4] = 1.f / (1.f + expf(-g0));
                    sh_n[5] = 1.f / (1.f + expf(-g1));
                    sh_n[6] = 1.f / (1.f + expf(-g2));
                    sh_n[7] = 1.f / (1.f + expf(-g3));
                }
            }
        }
        BAR();

        // ---- P4: blend (waves 4-7) || next h_tilde (waves 0-3) ------------
        if (tid >= H_) {
            const float a0 = sh_a[0], a1 = sh_a[1], a2 = sh_a[2];
            int q  = tid - H_;          // 0..255
            int d  = q >> 1;            // 0..127
            int v4 = (q & 1) * 4;
            float4 cur  = *(const float4*)&sh_st[p][d][v4];
            float4 push = (d == 0) ? *(const float4*)&sh_n[v4]
                                   : *(const float4*)&sh_st[p][d - 1][v4];
            float4 pop;
            if (d == D_ - 1) pop = make_float4(0.f, 0.f, 0.f, 0.f);
            else             pop = *(const float4*)&sh_st[p][d + 1][v4];
            float4 nw;
            nw.x = a0 * push.x + a1 * pop.x + a2 * cur.x;
            nw.y = a0 * push.y + a1 * pop.y + a2 * cur.y;
            nw.z = a0 * push.z + a1 * pop.z + a2 * cur.z;
            nw.w = a0 * push.w + a1 * pop.w + a2 * cur.w;
            *(float4*)&sh_st[p ^ 1][d][v4] = nw;
        } else {
            // new stack top recomputed redundantly in registers (rows 0,1 of
            // OLD buffer + n) so h_tilde needs no extra barrier.
            const float a0 = sh_a[0], a1 = sh_a[1], a2 = sh_a[2];
            float4 n0  = *(const float4*)&sh_n[0];
            float4 n1  = *(const float4*)&sh_n[4];
            float4 r00 = *(const float4*)&sh_st[p][0][0];
            float4 r01 = *(const float4*)&sh_st[p][0][4];
            float4 r10 = *(const float4*)&sh_st[p][1][0];
            float4 r11 = *(const float4*)&sh_st[p][1][4];
            float top[8];
            top[0] = a0 * n0.x + a1 * r10.x + a2 * r00.x;
            top[1] = a0 * n0.y + a1 * r10.y + a2 * r00.y;
            top[2] = a0 * n0.z + a1 * r10.z + a2 * r00.z;
            top[3] = a0 * n0.w + a1 * r10.w + a2 * r00.w;
            top[4] = a0 * n1.x + a1 * r11.x + a2 * r01.x;
            top[5] = a0 * n1.y + a1 * r11.y + a2 * r01.y;
            top[6] = a0 * n1.z + a1 * r11.z + a2 * r01.z;
            top[7] = a0 * n1.w + a1 * r11.w + a2 * r01.w;
            float ht = hidden_reg;
            #pragma unroll
            for (int v = 0; v < VD_; v++) ht = fmaf(top[v], wsh[v], ht);
            sh_h[tid] = ht;
        }
        BAR();
    }

    // T_ even -> final stack in buffer 0
    for (int q = tid; q < D_ * VD_; q += 512)
        out_stack[(size_t)b * D_ * VD_ + q] = (&sh_st[0][0][0])[q];
    if (tid < H_)
        out_hidden[(size_t)b * H_ + tid] = hidden_reg;
}

extern "C" void kernel_launch(void* const* d_in, const int* in_sizes, int n_in,
                              void* d_out, int out_size, void* d_ws, size_t ws_size,
                              hipStream_t stream) {
    const float* inputs  = (const float*)d_in[0];
    const float* stack0  = (const float*)d_in[1];
    const float* hidden0 = (const float*)d_in[2];
    const float* W_ih    = (const float*)d_in[3];
    const float* b_ih    = (const float*)d_in[4];
    const float* W_hh    = (const float*)d_in[5];
    const float* b_hh    = (const float*)d_in[6];
    const float* W_sh    = (const float*)d_in[7];
    const float* W_y     = (const float*)d_in[8];
    const float* W_a     = (const float*)d_in[9];
    const float* W_n     = (const float*)d_in[10];

    float* out = (float*)d_out;
    float* Z     = out;                                   // (B,T,H), consumed before overwrite
    float* H_all = (float*)d_ws;                          // (B,T,H)
    float* out_stack  = out + (size_t)B_ * T_ * V_;
    float* out_hidden = out_stack + (size_t)B_ * D_ * VD_;

    const int M = B_ * T_;   // 131072

    // 1) Z = inputs @ W_ih^T + b_ih     (M x 256, K=512)
    gemm_nt_kernel<<<dim3(M / 64, H_ / 256), 256, 0, stream>>>(
        inputs, W_ih, b_ih, Z, M, H_, V_);

    // 2) serial scan
    recurrence_kernel<<<dim3(B_), 512, 0, stream>>>(
        Z, stack0, hidden0, W_hh, b_hh, W_sh, W_a, W_n,
        H_all, out_stack, out_hidden);

    // 3) outputs = H_all @ W_y^T        (M x 512, K=256)
    gemm_nt_kernel<<<dim3(M / 64, V_ / 256), 256, 0, stream>>>(
        H_all, W_y, nullptr, out, M, V_, H_);
}